// Round 9
// baseline (228.046 us; speedup 1.0000x reference)
//
#include <hip/hip_runtime.h>

// SpikingCell recurrence, dead-code-eliminated (absmax=0 verified R0-R8):
//   dvi = (refrac >= 2) ? buf : 0
//   v += dvi; o = (v >= 1); v -= o
//   refrac = o ? 0 : refrac + 1
//   buf = x[b,t,n]
//
// R8 post-mortem: burst size invariant under NT too (R8 float4+NT == R6
// scalar+NT). NT was the only real win so far (L2-allocation interference,
// ~85 -> ~68 us). Residual vs linear-copy ceiling (6.3 TB/s): theory is
// fine-grained rd/wr phase alternation across a 32 KB-strided walk (DRAM
// row re-opens per phase switch, no L2 buffering under NT). R9: U=32
// phase batching on the R6 skeleton — 32 pure NT reads, then 32
// compute+NT-stores per group. 512 blocks x 256 thr, 8 waves/CU.

constexpr int B = 16;
constexpr int T = 256;
constexpr int N = 8192;
constexpr int U = 32;  // phase size in t-steps

__global__ __launch_bounds__(256, 2) void spiking_kernel(
    const float* __restrict__ x, float* __restrict__ out) {
  const int c = blockIdx.x * blockDim.x + threadIdx.x;  // 0 .. B*N-1
  const int b = c >> 13;      // c / N
  const int n = c & (N - 1);  // c % N

  const float* __restrict__ xp = x + (size_t)b * T * N + n;
  float* __restrict__ op = out + (size_t)b * T * N + n;

  float v = 0.f, refrac = 0.f, buf = 0.f;

  float cur[U], nxt[U];

#pragma unroll
  for (int u = 0; u < U; ++u)
    cur[u] = __builtin_nontemporal_load(xp + (size_t)u * N);

#pragma unroll 1
  for (int g = 0; g < T / U - 1; ++g) {
    // ---- read phase: 32 NT loads for group g+1 ----
    const size_t base_next = (size_t)(g + 1) * U * N;
#pragma unroll
    for (int u = 0; u < U; ++u)
      nxt[u] = __builtin_nontemporal_load(xp + base_next + (size_t)u * N);

    // ---- compute + write phase: 32 NT stores for group g ----
    const size_t base_cur = (size_t)g * U * N;
#pragma unroll
    for (int u = 0; u < U; ++u) {
      const float dvi = (refrac >= 2.0f) ? buf : 0.0f;
      v += dvi;
      const float o = (v >= 1.0f) ? 1.0f : 0.0f;
      v -= o;
      refrac = (o == 0.0f) ? (refrac + 1.0f) : 0.0f;
      buf = cur[u];
      __builtin_nontemporal_store(o, op + base_cur + (size_t)u * N);
    }

#pragma unroll
    for (int u = 0; u < U; ++u) cur[u] = nxt[u];
  }

  // Epilogue: last U timesteps.
  const size_t base_last = (size_t)(T - U) * N;
#pragma unroll
  for (int u = 0; u < U; ++u) {
    const float dvi = (refrac >= 2.0f) ? buf : 0.0f;
    v += dvi;
    const float o = (v >= 1.0f) ? 1.0f : 0.0f;
    v -= o;
    refrac = (o == 0.0f) ? (refrac + 1.0f) : 0.0f;
    buf = cur[u];
    __builtin_nontemporal_store(o, op + base_last + (size_t)u * N);
  }
}

extern "C" void kernel_launch(void* const* d_in, const int* in_sizes, int n_in,
                              void* d_out, int out_size, void* d_ws,
                              size_t ws_size, hipStream_t stream) {
  const float* x = (const float*)d_in[0];
  float* out = (float*)d_out;

  const int threads = 256;
  const int total = B * N;             // one thread per element
  const int blocks = total / threads;  // 512 blocks -> 2 blocks/CU, 8 waves/CU
  spiking_kernel<<<blocks, threads, 0, stream>>>(x, out);
}

// Round 10
// 227.388 us; speedup vs baseline: 1.0029x; 1.0029x over previous
//
#include <hip/hip_runtime.h>

// SpikingCell recurrence, dead-code-eliminated (absmax=0 verified R0-R9):
//   dvi = (refrac >= 2) ? buf : 0
//   v += dvi; o = (v >= 1); v -= o
//   refrac = o ? 0 : refrac + 1
//   buf = x[b,t,n]
//
// R9 post-mortem: rd/wr phase batching (U=32) neutral. Falsified so far:
// burst size (both regimes), waves/CU, prefetch mechanism, phase
// granularity. Only NT hints moved the needle (~85 -> ~68 us) — but R6
// applied NT to BOTH streams, and pre-NT counters showed FETCH=65 MB, i.e.
// half the reads were L3 hits that full-NT may forfeit. R10 decomposes:
// TEMPORAL loads (keep Infinity-Cache read hits) + NT stores (keep the
// write-allocation win). R6 skeleton otherwise unchanged (U=8 scalar,
// 512 blocks x 256, 8 waves/CU).

constexpr int B = 16;
constexpr int T = 256;
constexpr int N = 8192;
constexpr int U = 8;  // pipeline group size

__global__ __launch_bounds__(256, 2) void spiking_kernel(
    const float* __restrict__ x, float* __restrict__ out) {
  const int c = blockIdx.x * blockDim.x + threadIdx.x;  // 0 .. B*N-1
  const int b = c >> 13;      // c / N
  const int n = c & (N - 1);  // c % N

  const float* __restrict__ xp = x + (size_t)b * T * N + n;
  float* __restrict__ op = out + (size_t)b * T * N + n;

  float v = 0.f, refrac = 0.f, buf = 0.f;

  float cur[U], nxt[U];

#pragma unroll
  for (int u = 0; u < U; ++u) cur[u] = xp[(size_t)u * N];

#pragma unroll 1
  for (int g = 0; g < T / U - 1; ++g) {
    const size_t base_next = (size_t)(g + 1) * U * N;
#pragma unroll
    for (int u = 0; u < U; ++u) nxt[u] = xp[base_next + (size_t)u * N];

    const size_t base_cur = (size_t)g * U * N;
#pragma unroll
    for (int u = 0; u < U; ++u) {
      const float dvi = (refrac >= 2.0f) ? buf : 0.0f;
      v += dvi;
      const float o = (v >= 1.0f) ? 1.0f : 0.0f;
      v -= o;
      refrac = (o == 0.0f) ? (refrac + 1.0f) : 0.0f;
      buf = cur[u];
      __builtin_nontemporal_store(o, op + base_cur + (size_t)u * N);
    }

#pragma unroll
    for (int u = 0; u < U; ++u) cur[u] = nxt[u];
  }

  // Epilogue: last U timesteps.
  const size_t base_last = (size_t)(T - U) * N;
#pragma unroll
  for (int u = 0; u < U; ++u) {
    const float dvi = (refrac >= 2.0f) ? buf : 0.0f;
    v += dvi;
    const float o = (v >= 1.0f) ? 1.0f : 0.0f;
    v -= o;
    refrac = (o == 0.0f) ? (refrac + 1.0f) : 0.0f;
    buf = cur[u];
    __builtin_nontemporal_store(o, op + base_last + (size_t)u * N);
  }
}

extern "C" void kernel_launch(void* const* d_in, const int* in_sizes, int n_in,
                              void* d_out, int out_size, void* d_ws,
                              size_t ws_size, hipStream_t stream) {
  const float* x = (const float*)d_in[0];
  float* out = (float*)d_out;

  const int threads = 256;
  const int total = B * N;             // one thread per element
  const int blocks = total / threads;  // 512 blocks -> 2 blocks/CU, 8 waves/CU
  spiking_kernel<<<blocks, threads, 0, stream>>>(x, out);
}